// Round 5
// baseline (528.664 us; speedup 1.0000x reference)
//
#include <hip/hip_runtime.h>
#include <cstdint>
#include <cstddef>

#define GK0 0.7978845608028654f
#define GC1 0.044715f

typedef __attribute__((ext_vector_type(8))) short short8;
typedef __attribute__((ext_vector_type(4))) float floatx4;

__device__ __forceinline__ unsigned short f2bf(float f) {
  union { float f; unsigned int u; } v; v.f = f;
  unsigned int r = v.u + 0x7fffu + ((v.u >> 16) & 1u);   // RNE
  return (unsigned short)(r >> 16);
}

// async 16B global->LDS (LDS dest = wave-uniform base + lane*16; global src per-lane)
__device__ __forceinline__ void gl_lds16(const unsigned short* g, unsigned short* l) {
  __builtin_amdgcn_global_load_lds(
      (const __attribute__((address_space(1))) unsigned int*)g,
      (__attribute__((address_space(3))) unsigned int*)l, 16, 0, 0);
}

// ---- weights: [co][ci][3][3] f32 -> wt[khw][co][ci] bf16; also zero out ----
__global__ void k_wt(const float* __restrict__ w, unsigned short* __restrict__ wt,
                     float* __restrict__ out) {
  if (blockIdx.x == 0) {
    for (int i = threadIdx.x; i < 32 * 128; i += 256) out[i] = 0.0f;
  }
  int t = blockIdx.x * 256 + threadIdx.x;
  if (t >= 128 * 64 * 9) return;
  int co = t / 576; int r = t - co * 576; int ci = r / 9; int khw = r - ci * 9;
  wt[(khw * 128 + co) * 64 + ci] = f2bf(w[t]);
}

// ---- resident-grid rolling implicit-GEMM conv + fused bias/GELU/pool ----
// grid (2 w-halves, 8 h-groups, 32 b) = 512 blocks = EXACTLY 2/CU, one dispatch
// round (R4's 4032 tiny blocks paid ~72k cyc each for ~11k of work: per-block
// prologue latency + zero row reuse). Block rolls over 8 h-pairs with a 4-slot
// circular row buffer: per pair only 2 NEW rows staged (re-stage ratio 4x -> 1.13x).
// T14 split: next-pair row loads issued during kh=0, packed bf16 in regs, written
// after the post-kh1 barrier into slots provably dead (row 2hp dies after kh0,
// row 2hp+1 after kh1). 2 barriers/pair. A: wave-private 8KB single-buffer staged
// per tap via gl_lds16 + own-wave lgkm/vmcnt fences (R4-proven, no cross-wave sync).
__global__ __launch_bounds__(256, 2) void k_conv(
    const float* __restrict__ x, const unsigned short* __restrict__ wt,
    const float* __restrict__ bias, float* __restrict__ out) {
  __shared__ __align__(16) unsigned short Bs[4][4608];       // 4 row-slots [72p][64ci]
  __shared__ __align__(16) unsigned short As[4][4096];       // 4 waves x 8 KB private
  const int tid = threadIdx.x, lane = tid & 63, wv = tid >> 6;
  const int w0 = blockIdx.x * 64, g = blockIdx.y, b = blockIdx.z;
  const int npair = (g < 7) ? 8 : 7;                         // 63 pairs total
  const int wm = wv & 1, wn = wv >> 1;                       // co-half, h-row
  const int m = lane & 15, q = lane >> 4;
  unsigned short* Asw = As[wv];

  // stage-source pre-swizzle: LDS (row, grp) holds wt[row][grp ^ (row&7)]
  const int srcswz = (lane >> 3) * 64 + (((lane & 7) ^ (lane >> 3)) << 3);
  auto stageA = [&](int khw) {                               // own co-half: 8 KB
    const unsigned short* src = wt + khw * 8192 + wm * 4096 + srcswz;
#pragma unroll
    for (int c = 0; c < 8; c++) gl_lds16(src + c * 512, Asw + c * 512);
  };

  const float* xg = x + (size_t)b * 64 * 16384 + (size_t)(16 * g) * 128;

  float bvv[4][4];
#pragma unroll
  for (int mt = 0; mt < 4; mt++)
#pragma unroll
    for (int r2 = 0; r2 < 4; r2++)
      bvv[mt][r2] = bias[wm * 64 + mt * 16 + q * 4 + r2];

  floatx4 acc[4][4];
  float pool[4][4];
#pragma unroll
  for (int i = 0; i < 4; i++)
#pragma unroll
    for (int j = 0; j < 4; j++) {
      acc[i][j] = (floatx4){0.f, 0.f, 0.f, 0.f};
      pool[i][j] = 0.f;
    }

  stageA(0);                                                 // lands under prologue

  // ---- prologue: rows 0..3, 4608 float4-units = 18/thread, 3 batches of 6 ----
  // LDS elem (slot, p, c') = input[row][p][c' ^ ((p&7)<<3)]
#pragma unroll
  for (int t3 = 0; t3 < 3; t3++) {
    float4 u6[6];
#pragma unroll
    for (int j = 0; j < 6; j++) {
      const int u = (t3 * 6 + j) * 256 + tid;
      const int r = u / 1152, rem = u - r * 1152;
      const int ci = rem / 18, ch = rem - ci * 18;
      u6[j] = *(const float4*)(xg + (size_t)ci * 16384 + r * 128 + min(w0 + 4 * ch, 124));
    }
#pragma unroll
    for (int j = 0; j < 6; j++) {
      const int u = (t3 * 6 + j) * 256 + tid;
      const int r = u / 1152, rem = u - r * 1152;
      const int ci = rem / 18, ch = rem - ci * 18;
      union { float4 v4; float f[4]; } fu; fu.v4 = u6[j];
#pragma unroll
      for (int e = 0; e < 4; e++) {
        const int p = 4 * ch + e;
        Bs[r][p * 64 + (ci ^ ((p & 7) << 3))] = f2bf(fu.f[e]);
      }
    }
  }
  __syncthreads();                                           // B rows 0-3 + A0 ready

  for (int hp = 0; hp < npair; hp++) {
    const int more = (hp + 1 < npair);
    float4 ru[9];
    unsigned int pk[9][2];
#pragma unroll
    for (int kh = 0; kh < 3; kh++) {
#pragma unroll
      for (int kw = 0; kw < 3; kw++) {
        const int khw = kh * 3 + kw;
        const unsigned short* bcur = Bs[(2 * hp + wn + kh) & 3];
        short8 a[2][4], bf[2][4];
#pragma unroll
        for (int half = 0; half < 2; half++) {
          const int colb = half * 32 + q * 8;
#pragma unroll
          for (int mt = 0; mt < 4; mt++)
            a[half][mt] =
                *(const short8*)(Asw + (mt * 16 + m) * 64 + (colb ^ ((m & 7) << 3)));
#pragma unroll
          for (int nt = 0; nt < 4; nt++)
            bf[half][nt] = *(const short8*)(bcur + (nt * 16 + m + kw) * 64 +
                                            (colb ^ (((m + kw) & 7) << 3)));
        }
        asm volatile("s_waitcnt lgkmcnt(0)" ::: "memory");   // reads in regs;
        if (!(hp == npair - 1 && khw == 8))                  // safe to overwrite Asw
          stageA((khw + 1) % 9);
#pragma unroll
        for (int half = 0; half < 2; half++)
#pragma unroll
          for (int mt = 0; mt < 4; mt++)
#pragma unroll
            for (int nt = 0; nt < 4; nt++)
              acc[mt][nt] = __builtin_amdgcn_mfma_f32_16x16x32_bf16(
                  a[half][mt], bf[half][nt], acc[mt][nt], 0, 0, 0);
        asm volatile("s_waitcnt vmcnt(0)" ::: "memory");     // own A-stage landed
        if (khw == 0 && more) {                              // T14: issue next-pair
#pragma unroll                                               // row loads (held in regs)
          for (int k = 0; k < 9; k++) {
            const int u = k * 256 + tid;
            const int r2 = u / 1152, rem = u - r2 * 1152;
            const int ci = rem / 18, ch = rem - ci * 18;
            ru[k] = *(const float4*)(xg + (size_t)ci * 16384 +
                                     (2 * hp + 4 + r2) * 128 + min(w0 + 4 * ch, 124));
          }
        }
        if (khw == 5 && more) {                              // pack f32->bf16 (halves
#pragma unroll                                               // reg liveness for write)
          for (int k = 0; k < 9; k++) {
            union { float4 v4; float f[4]; } fu; fu.v4 = ru[k];
            pk[k][0] = (unsigned)f2bf(fu.f[0]) | ((unsigned)f2bf(fu.f[1]) << 16);
            pk[k][1] = (unsigned)f2bf(fu.f[2]) | ((unsigned)f2bf(fu.f[3]) << 16);
          }
        }
      }
      if (kh == 1) {
        __syncthreads();                                     // #1: rows 2hp,2hp+1 dead
        if (more) {                                          // write rows 2hp+4,2hp+5
#pragma unroll
          for (int k = 0; k < 9; k++) {
            const int u = k * 256 + tid;
            const int rw = u / 1152, rem = u - rw * 1152;
            const int ci = rem / 18, ch = rem - ci * 18;
            unsigned short* dst = Bs[(2 * hp + rw) & 3];     // dead slots
#pragma unroll
            for (int e = 0; e < 4; e++) {
              const int p = 4 * ch + e;
              dst[p * 64 + (ci ^ ((p & 7) << 3))] =
                  (unsigned short)((pk[k][e >> 1] >> ((e & 1) * 16)) & 0xffffu);
            }
          }
        }
      }
    }
    // per-pair epilogue: bias + fast tanh-GELU into pool regs, reset acc
#pragma unroll
    for (int mt = 0; mt < 4; mt++)
#pragma unroll
      for (int r2 = 0; r2 < 4; r2++) {
        float s = 0.f;
#pragma unroll
        for (int nt = 0; nt < 4; nt++) {
          float y = acc[mt][nt][r2] + bvv[mt][r2];
          float u = GK0 * (y + GC1 * y * y * y);
          float e = __expf(-2.0f * u);
          float gl = y * __builtin_amdgcn_rcpf(1.0f + e);    // == 0.5y(1+tanh u)
          if (w0 + nt * 16 + m < 126) s += gl;               // mask padded w'
          acc[mt][nt][r2] = 0.f;
        }
        pool[mt][r2] += s;
      }
    __syncthreads();                                         // #2: pair end (staged
  }                                                          // writes visible)

  // block epilogue: reduce over m-lanes, one atomicAdd set per block
  const float inv_area = 1.0f / (126.0f * 126.0f);
  float* orow = out + b * 128;
#pragma unroll
  for (int mt = 0; mt < 4; mt++)
#pragma unroll
    for (int r2 = 0; r2 < 4; r2++) {
      float s = pool[mt][r2];
#pragma unroll
      for (int d = 1; d < 16; d <<= 1) s += __shfl_xor(s, d, 64);
      if (m == 0) atomicAdd(&orow[wm * 64 + mt * 16 + q * 4 + r2], s * inv_area);
    }
}

extern "C" void kernel_launch(void* const* d_in, const int* in_sizes, int n_in,
                              void* d_out, int out_size, void* d_ws, size_t ws_size,
                              hipStream_t stream) {
  const float* x    = (const float*)d_in[0];
  const float* w    = (const float*)d_in[1];
  const float* bias = (const float*)d_in[2];
  float* out = (float*)d_out;

  unsigned short* wbuf = (unsigned short*)d_ws;              // 144 KB weights only
  if (ws_size < (size_t)9 * 128 * 64 * 2 + 4096) return;

  k_wt<<<288, 256, 0, stream>>>(w, wbuf, out);
  k_conv<<<dim3(2, 8, 32), 256, 0, stream>>>(x, wbuf, bias, out);
}

// Round 6
// 372.290 us; speedup vs baseline: 1.4200x; 1.4200x over previous
//
#include <hip/hip_runtime.h>
#include <cstdint>
#include <cstddef>

#define GK0 0.7978845608028654f
#define GC1 0.044715f

typedef __attribute__((ext_vector_type(8))) short short8;
typedef __attribute__((ext_vector_type(4))) float floatx4;

__device__ __forceinline__ unsigned short f2bf(float f) {
  union { float f; unsigned int u; } v; v.f = f;
  unsigned int r = v.u + 0x7fffu + ((v.u >> 16) & 1u);   // RNE
  return (unsigned short)(r >> 16);
}

// async 16B global->LDS (LDS dest = wave-uniform base + lane*16; global src per-lane)
__device__ __forceinline__ void gl_lds16(const unsigned short* g, unsigned short* l) {
  __builtin_amdgcn_global_load_lds(
      (const __attribute__((address_space(1))) unsigned int*)g,
      (__attribute__((address_space(3))) unsigned int*)l, 16, 0, 0);
}

// ---- weights: [co][ci][3][3] f32 -> wt[khw][co][ci] bf16; also zero out ----
__global__ void k_wt(const float* __restrict__ w, unsigned short* __restrict__ wt,
                     float* __restrict__ out) {
  if (blockIdx.x == 0) {
    for (int i = threadIdx.x; i < 32 * 128; i += 256) out[i] = 0.0f;
  }
  int t = blockIdx.x * 256 + threadIdx.x;
  if (t >= 128 * 64 * 9) return;
  int co = t / 576; int r = t - co * 576; int ci = r / 9; int khw = r - ci * 9;
  wt[(khw * 128 + co) * 64 + ci] = f2bf(w[t]);
}

// ---- single-pass implicit-GEMM conv + fused transpose/bias/GELU/pool ----
// R4 skeleton (best measured) with LDS cut 69.6 KB -> 51.2 KB => 3 blocks/CU
// (12 waves, +50% latency hiding; R4's deficit was overlap, not throughput).
// Bs: TWO rolling row-slots (row h0+X -> slot X&1): kh reads slots {kh,kh+1}&1,
// end-of-kh overwrites slot kh&1 with row h0+kh+2 -- zero copies, 1 new row/kh.
// Next-row f32 loads issued at kw0 (5 float4 = 20 VGPR, live ~2 taps -- R5's
// spill disaster was 54 VGPR held forever; WRITE_SIZE is the tripwire).
// A: wave-private 8 KB staged per tap via gl_lds16 + own-wave fences (R4-proven).
__global__ __launch_bounds__(256, 3) void k_conv(
    const float* __restrict__ x, const unsigned short* __restrict__ wt,
    const float* __restrict__ bias, float* __restrict__ out) {
  __shared__ __align__(16) unsigned short Bs[2][4608];       // 2 slots [72p][64ci]
  __shared__ __align__(16) unsigned short As[4][4096];       // 4 waves x 8 KB private
  const int tid = threadIdx.x, lane = tid & 63, wv = tid >> 6;
  const int w0 = blockIdx.x * 64, h0 = blockIdx.y * 2, b = blockIdx.z;
  const int wm = wv & 1, wn = wv >> 1;                       // co-half, h-row
  const int m = lane & 15, q = lane >> 4;
  unsigned short* Asw = As[wv];

  // stage-source pre-swizzle: LDS (row, grp) holds wt[row][grp ^ (row&7)]
  const int srcswz = (lane >> 3) * 64 + (((lane & 7) ^ (lane >> 3)) << 3);
  auto stageA = [&](int khw) {                               // own co-half: 8 KB
    const unsigned short* src = wt + khw * 8192 + wm * 4096 + srcswz;
#pragma unroll
    for (int c = 0; c < 8; c++) gl_lds16(src + c * 512, Asw + c * 512);
  };

  const float* xb0 = x + (size_t)b * 64 * 16384;             // +ci*16384+h*128+w

  stageA(0);                                                 // lands under prologue

  // ---- prologue: rows h0,h0+1 -> slots 0,1 ; 2304 float4 = 9/thread, 1 batch ----
  // LDS elem (slot, p, c') = input[row][p][c' ^ ((p&7)<<3)]
  {
    float4 pu[9];
#pragma unroll
    for (int k = 0; k < 9; k++) {
      const int u = k * 256 + tid;
      const int r = u / 1152, rem = u - r * 1152;
      const int ci = rem / 18, ch = rem - ci * 18;
      pu[k] = *(const float4*)(xb0 + (size_t)ci * 16384 + (h0 + r) * 128 +
                               min(w0 + 4 * ch, 124));       // clamp: dup, masked out
    }
#pragma unroll
    for (int k = 0; k < 9; k++) {
      const int u = k * 256 + tid;
      const int r = u / 1152, rem = u - r * 1152;
      const int ci = rem / 18, ch = rem - ci * 18;
      union { float4 v4; float f[4]; } fu; fu.v4 = pu[k];
#pragma unroll
      for (int e = 0; e < 4; e++) {
        const int p = 4 * ch + e;
        Bs[r][p * 64 + (ci ^ ((p & 7) << 3))] = f2bf(fu.f[e]);
      }
    }
  }

  floatx4 acc[4][4];
#pragma unroll
  for (int i = 0; i < 4; i++)
#pragma unroll
    for (int j = 0; j < 4; j++) acc[i][j] = (floatx4){0.f, 0.f, 0.f, 0.f};

  __syncthreads();                                           // B rows 0,1 + A0 ready

  float4 nu[5];
#pragma unroll
  for (int kh = 0; kh < 3; kh++) {
#pragma unroll
    for (int kw = 0; kw < 3; kw++) {
      const int t = kh * 3 + kw;
      const unsigned short* bcur = Bs[(wn + kh) & 1];        // row h0+wn+kh
      short8 a[2][4], bf[2][4];
#pragma unroll
      for (int half = 0; half < 2; half++) {
        const int colb = half * 32 + q * 8;
#pragma unroll
        for (int mt = 0; mt < 4; mt++)
          a[half][mt] =
              *(const short8*)(Asw + (mt * 16 + m) * 64 + (colb ^ ((m & 7) << 3)));
#pragma unroll
        for (int nt = 0; nt < 4; nt++)
          bf[half][nt] = *(const short8*)(bcur + (nt * 16 + m + kw) * 64 +
                                          (colb ^ (((m + kw) & 7) << 3)));
      }
      asm volatile("s_waitcnt lgkmcnt(0)" ::: "memory");     // frags in regs
      if (kw == 0 && kh < 2) {                               // next row (h0+kh+2),
#pragma unroll                                               // 5 float4, short-lived
        for (int k = 0; k < 5; k++) {
          const int u = k * 256 + tid;
          if (u < 1152) {
            const int ci = u / 18, ch = u - ci * 18;
            nu[k] = *(const float4*)(xb0 + (size_t)ci * 16384 + (h0 + kh + 2) * 128 +
                                     min(w0 + 4 * ch, 124));
          }
        }
      }
      if (t < 8) stageA(t + 1);                              // overwrite own A (dead)
#pragma unroll
      for (int half = 0; half < 2; half++)
#pragma unroll
        for (int mt = 0; mt < 4; mt++)
#pragma unroll
          for (int nt = 0; nt < 4; nt++)
            acc[mt][nt] = __builtin_amdgcn_mfma_f32_16x16x32_bf16(
                a[half][mt], bf[half][nt], acc[mt][nt], 0, 0, 0);
      asm volatile("s_waitcnt vmcnt(0)" ::: "memory");       // own A-stage (+nu) done
    }
    if (kh < 2) {
      __syncthreads();                                       // slot kh&1 reads done
#pragma unroll
      for (int k = 0; k < 5; k++) {                          // write row h0+kh+2
        const int u = k * 256 + tid;
        if (u < 1152) {
          const int ci = u / 18, ch = u - ci * 18;
          union { float4 v4; float f[4]; } fu; fu.v4 = nu[k];
#pragma unroll
          for (int e = 0; e < 4; e++) {
            const int p = 4 * ch + e;
            Bs[kh & 1][p * 64 + (ci ^ ((p & 7) << 3))] = f2bf(fu.f[e]);
          }
        }
      }
      __syncthreads();                                       // new row visible
    }
  }

  // epilogue: bias + fast tanh-GELU (y*sigmoid(2u)) + masked pool
  // D layout: col n = wn*64 + nt*16 + (lane&15) -> w' = nt*16+m; row co = q*4+r
  const float inv_area = 1.0f / (126.0f * 126.0f);
  float* orow = out + b * 128;
#pragma unroll
  for (int mt = 0; mt < 4; mt++)
#pragma unroll
    for (int r2 = 0; r2 < 4; r2++) {
      const int co = wm * 64 + mt * 16 + q * 4 + r2;
      const float bv = bias[co];
      float s = 0.f;
#pragma unroll
      for (int nt = 0; nt < 4; nt++) {
        float y = acc[mt][nt][r2] + bv;
        float u = GK0 * (y + GC1 * y * y * y);
        float e = __expf(-2.0f * u);
        float g = y * __builtin_amdgcn_rcpf(1.0f + e);       // == 0.5y(1+tanh u)
        if (w0 + nt * 16 + m < 126) s += g;                  // mask padded w'
      }
#pragma unroll
      for (int d = 1; d < 16; d <<= 1) s += __shfl_xor(s, d, 64);
      if (m == 0) atomicAdd(&orow[co], s * inv_area);
    }
}

extern "C" void kernel_launch(void* const* d_in, const int* in_sizes, int n_in,
                              void* d_out, int out_size, void* d_ws, size_t ws_size,
                              hipStream_t stream) {
  const float* x    = (const float*)d_in[0];
  const float* w    = (const float*)d_in[1];
  const float* bias = (const float*)d_in[2];
  float* out = (float*)d_out;

  unsigned short* wbuf = (unsigned short*)d_ws;              // 144 KB weights only
  if (ws_size < (size_t)9 * 128 * 64 * 2 + 4096) return;

  k_wt<<<288, 256, 0, stream>>>(w, wbuf, out);
  k_conv<<<dim3(2, 63, 32), 256, 0, stream>>>(x, wbuf, bias, out);
}